// Round 11
// baseline (165.667 us; speedup 1.0000x reference)
//
#include <hip/hip_runtime.h>
#include <math.h>

#define BATCH 8192
typedef unsigned short u16;
typedef unsigned int u32;
typedef _Float16 f16;
typedef __attribute__((ext_vector_type(8))) _Float16 f16x8;
typedef __attribute__((ext_vector_type(4))) float f32x4;
typedef __attribute__((ext_vector_type(4))) unsigned short u16x4;

__device__ __forceinline__ float sigm(float v) { return __fdividef(1.0f, 1.0f + __expf(-v)); }
__device__ __forceinline__ float tanh_fast(float x) {
    float e = __expf(2.0f * fminf(x, 15.0f));          // clamp avoids inf/inf
    return __fdividef(e - 1.0f, e + 1.0f);
}
__device__ __forceinline__ u16 f2h(float f) {
    union { f16 h; u16 u; } v; v.h = (f16)f;   // v_cvt_f16_f32, RNE
    return v.u;
}
// fragment-linear B: element [(nt*nch + ch)*64 + lane]*8 + e  ==  B[nt*16+(lane&15)][ch*32+(lane>>4)*8+e]
__device__ __forceinline__ f16x8 ffrag(const u16* Bf, int nt, int ch, int nch, int lane) {
    return *(const f16x8*)(Bf + (((size_t)nt * nch + ch) * 64 + lane) * 8);
}
#define MFMA16(a, b, c) __builtin_amdgcn_mfma_f32_16x16x32_f16(a, b, c, 0, 0, 0)

// ---------------- workspace layout (u16 elements, fp16, SINGLE plane) ----------------
#define S_FBT 69632   // [17 nt][8 ch] frag-linear, n<272, k<256
#define S_B1  61440   // 3 taps x [8 nt][5 ch], n<128, k<160
#define S_B2A 16384   // [4 nt][8 ch]
#define S_B2B 24576   // [4 nt][12 ch]
#define S_B3  8192    // [4 nt][4 ch]
#define S_B4  8192    // [8 nt][2 ch]
#define S_BL  131072  // [32 nt][8 ch]  n = gate*128+j, k: 0..127 W / 128..255 U
#define P_FBT 0
#define P_B1  69632
#define P_B2A 131072
#define P_B2B 147456
#define P_B3  172032
#define P_B4  180224
#define P_BL  188416
#define N_PREP 319488

// ---------------- k_prep: build fragment-linear fp16 B planes ----------------
__global__ __launch_bounds__(256) void k_prep(const float* __restrict__ fb,
                                              const float* __restrict__ w1, const float* __restrict__ w2,
                                              const float* __restrict__ w3, const float* __restrict__ w4,
                                              const float* __restrict__ wi, const float* __restrict__ wf,
                                              const float* __restrict__ wg, const float* __restrict__ wo,
                                              const float* __restrict__ ui, const float* __restrict__ uf,
                                              const float* __restrict__ ug, const float* __restrict__ uo,
                                              u16* __restrict__ wsu) {
    const float* Ws[8] = {wi, wf, wg, wo, ui, uf, ug, uo};
    for (int i = blockIdx.x * 256 + threadIdx.x; i < N_PREP; i += gridDim.x * 256) {
        int r = i;
        float v; int P, idx;
        if (r < S_FBT) {                                    // FBT nch=8
            int f = r >> 9, lane = (r & 511) >> 3, e = r & 7;
            int n = (f >> 3) * 16 + (lane & 15), k = (f & 7) * 32 + (lane >> 4) * 8 + e;
            int c = n >> 1, part = n & 1;
            v = (n < 258) ? fb[(size_t)(c + part * 129) * 256 + k] : 0.f;
            P = P_FBT; idx = r;
        } else if ((r -= S_FBT) < S_B1) {                   // B1: 3 taps, nch=5
            int kk = r / 20480, r2 = r - kk * 20480;
            int f = r2 >> 9, lane = (r2 & 511) >> 3, e = r2 & 7;
            int n = (f / 5) * 16 + (lane & 15), k = (f % 5) * 32 + (lane >> 4) * 8 + e;
            v = (k < 129) ? w1[(size_t)n * 387 + k * 3 + kk] : 0.f;
            P = P_B1; idx = r;
        } else if ((r -= S_B1) < S_B2A) {                   // B2A nch=8
            int f = r >> 9, lane = (r & 511) >> 3, e = r & 7;
            int n = (f >> 3) * 16 + (lane & 15), k = (f & 7) * 32 + (lane >> 4) * 8 + e;
            v = w2[(size_t)n * 384 + (k & 127) * 3 + (k >> 7) + 1];
            P = P_B2A; idx = r;
        } else if ((r -= S_B2A) < S_B2B) {                  // B2B nch=12
            int f = r >> 9, lane = (r & 511) >> 3, e = r & 7;
            int n = (f / 12) * 16 + (lane & 15), k = (f % 12) * 32 + (lane >> 4) * 8 + e;
            v = w2[(size_t)n * 384 + (k & 127) * 3 + (k >> 7)];
            P = P_B2B; idx = r;
        } else if ((r -= S_B2B) < S_B3) {                   // B3 nch=4
            int f = r >> 9, lane = (r & 511) >> 3, e = r & 7;
            int n = (f >> 2) * 16 + (lane & 15), k = (f & 3) * 32 + (lane >> 4) * 8 + e;
            v = w3[(size_t)n * 192 + (k & 63) * 3 + (k >> 6) + 1];
            P = P_B3; idx = r;
        } else if ((r -= S_B3) < S_B4) {                    // B4 nch=2
            int f = r >> 9, lane = (r & 511) >> 3, e = r & 7;
            int n = (f >> 1) * 16 + (lane & 15), k = (f & 1) * 32 + (lane >> 4) * 8 + e;
            v = w4[(size_t)n * 192 + k * 3 + 1];
            P = P_B4; idx = r;
        } else {                                            // BL nch=8
            r -= S_B4;
            int f = r >> 9, lane = (r & 511) >> 3, e = r & 7;
            int n = (f >> 3) * 16 + (lane & 15), k = (f & 7) * 32 + (lane >> 4) * 8 + e;
            int g = n >> 7, j = n & 127;
            v = Ws[g + ((k >= 128) ? 4 : 0)][(size_t)j * 128 + (k & 127)];
            P = P_BL; idx = r;
        }
        wsu[P + idx] = f2h(v);
    }
}

// ---------------- k_all ----------------
// r10 structure (7 barriers, fp16 single-MFMA, K-split dual accs, same-phase hoists)
// + round-11:
//   (a) GEMM1 load-balance: tile16 (STFT rows 256..271, only c=128 useful) mt-split
//       across waves 0-3 (8 MFMAs each) instead of all on wave 7. Max MFMAs/wave in
//       GEMM1: 96 -> 72; barrier [2] no longer waits on an overloaded wave 7.
//       Same per-output accumulation order -> bit-identical.
//   (b) LSTM transcendentals: tanhf -> clamped __expf-based tanh_fast; divisions ->
//       __fdividef. Only numeric change (absmax ~0.0073 +- 1e-3 expected).
__global__ __launch_bounds__(512, 4) void k_all(const float* __restrict__ audio,
                                             const u16* __restrict__ wsu,
                                             const float* __restrict__ hin, const float* __restrict__ cin,
                                             const float* __restrict__ b1, const float* __restrict__ b2,
                                             const float* __restrict__ b3, const float* __restrict__ b4,
                                             const float* __restrict__ bxi, const float* __restrict__ bxf,
                                             const float* __restrict__ bxg, const float* __restrict__ bxo,
                                             const float* __restrict__ bhi, const float* __restrict__ bhf,
                                             const float* __restrict__ bhg, const float* __restrict__ bho,
                                             const float* __restrict__ cw, const float* __restrict__ cb,
                                             float* __restrict__ out) {
    __shared__ __align__(16) u16 uni[31872];
    u16* aA = uni;
    u16* eA = uni;
    u16* mA = uni + 11520;
    u16* s2 = uni + 11520;
    u16* s3 = uni + 13696;
    float* pr = (float*)(uni + 14848);
    u16* xh = uni + 27648;
    const int tid = threadIdx.x;
    const int b0 = blockIdx.x << 4;
    const int lane = tid & 63, w = tid >> 6;
    const int m = lane & 15, quad = lane >> 4;
    // ---- phase A: stage audio + zero mag plane + stage h ----
    for (int i = tid; i < 16 * 160; i += 512) {
        int bb = i / 160, j4 = (i - bb * 160) * 4;
        const float* ap = audio + (size_t)(b0 + bb) * 576;
        float4 v;
        if (j4 < 576) v = *(const float4*)(ap + j4);
        else { v.x = ap[1150 - j4]; v.y = ap[1149 - j4]; v.z = ap[1148 - j4]; v.w = ap[1147 - j4]; }
        int phys = bb * 720 + j4 + (j4 >> 7) * 8;
        u16x4 hv = {f2h(v.x), f2h(v.y), f2h(v.z), f2h(v.w)};
        *(u16x4*)(aA + phys) = hv;
    }
    for (int i = tid; i < 8064; i += 512) ((u32*)mA)[i] = 0u;    // zero mag (pads)
    for (int i = tid; i < 16 * 32; i += 512) {
        int row = i >> 5, c4 = (i & 31) * 4;
        float4 v = *(const float4*)(hin + (size_t)(b0 + row) * 128 + c4);
        u16x4 hv = {f2h(v.x), f2h(v.y), f2h(v.z), f2h(v.w)};
        *(u16x4*)(xh + row * 264 + 128 + c4) = hv;
    }
    __syncthreads();                                             // [1]
    // ---- GEMM1 (STFT): wave w owns nt = 2w..2w+1; tile16 mt-split on waves 0-3 ----
    const u16* fbT = wsu + P_FBT;
    f32x4 acc[4][2];
    f32x4 acc16 = (f32x4){0.f, 0.f, 0.f, 0.f};
    #pragma unroll
    for (int mt = 0; mt < 4; ++mt)
        #pragma unroll
        for (int t = 0; t < 2; ++t) acc[mt][t] = (f32x4){0.f, 0.f, 0.f, 0.f};
    for (int ch = 0; ch < 8; ++ch) {
        f16x8 ah[4];
        #pragma unroll
        for (int mt = 0; mt < 4; ++mt) {
            int Rm = mt * 16 + m;
            int phys = (Rm >> 2) * 720 + (Rm & 3) * 136 + ch * 32 + quad * 8 + ((ch >= 4) ? 8 : 0);
            ah[mt] = *(const f16x8*)(aA + phys);
        }
        #pragma unroll
        for (int tt = 0; tt < 2; ++tt) {
            f16x8 bh = ffrag(fbT, w * 2 + tt, ch, 8, lane);
            #pragma unroll
            for (int mt = 0; mt < 4; ++mt)
                acc[mt][tt] = MFMA16(ah[mt], bh, acc[mt][tt]);
        }
        if (w < 4) {                                  // tile16, fragment mt = w
            f16x8 bh16 = ffrag(fbT, 16, ch, 8, lane);
            acc16 = MFMA16(ah[w], bh16, acc16);
        }
    }
    // ---- magnitude epilogue -> mag LDS (no barrier: disjoint per-wave cells) ----
    #pragma unroll
    for (int tt = 0; tt < 2; ++tt) {
        int n = (w * 2 + tt) * 16 + m;
        #pragma unroll
        for (int mt = 0; mt < 4; ++mt)
            #pragma unroll
            for (int r = 0; r < 4; ++r) {
                float vv = acc[mt][tt][r];
                float s = vv * vv;
                s += __shfl_xor(s, 1);
                if (!(n & 1)) {
                    int R = mt * 16 + quad * 4 + r;
                    int bb = R >> 2, t = R & 3, c = n >> 1;
                    mA[(bb * 6 + t + 1) * 168 + c] = f2h(sqrtf(s));
                }
            }
    }
    if (w < 4) {                                      // tile16 epilogue (rows mt = w)
        int n = 256 + m;
        #pragma unroll
        for (int r = 0; r < 4; ++r) {
            float vv = acc16[r];
            float s = vv * vv;
            s += __shfl_xor(s, 1);
            if (!(n & 1)) {
                int R = w * 16 + quad * 4 + r;
                int bb = R >> 2, t = R & 3, c = n >> 1;
                mA[(bb * 6 + t + 1) * 168 + c] = f2h(sqrtf(s));
            }
        }
    }
    // ---- prefetch enc1 B (15 frags) before barrier (harmless if sunk) ----
    const u16* B1p = wsu + P_B1;
    f16x8 pB1[15];
    #pragma unroll
    for (int kk = 0; kk < 3; ++kk)
        #pragma unroll
        for (int ch = 0; ch < 5; ++ch)
            pB1[kk * 5 + ch] = ffrag(B1p + kk * 20480, w, ch, 5, lane);
    __syncthreads();                                             // [2]
    // ---- GEMM2 (enc1): b1 hoisted to phase top; wave w owns nt = w, mt=4 ----
    const float b1v = b1[w * 16 + m];
    f32x4 acc2[4];
    #pragma unroll
    for (int mt = 0; mt < 4; ++mt) acc2[mt] = (f32x4){0.f, 0.f, 0.f, 0.f};
    #pragma unroll
    for (int kk = 0; kk < 3; ++kk) {
        #pragma unroll
        for (int ch = 0; ch < 5; ++ch) {
            f16x8 bh = pB1[kk * 5 + ch];
            #pragma unroll
            for (int mt = 0; mt < 4; ++mt) {
                int Rm = mt * 16 + m;
                int phys = ((Rm >> 2) * 6 + (Rm & 3) + kk) * 168 + ch * 32 + quad * 8;
                f16x8 ah = *(const f16x8*)(mA + phys);
                acc2[mt] = MFMA16(ah, bh, acc2[mt]);
            }
        }
    }
    // ---- e1 -> eA (aliases dead audio; no barrier) ----
    {
        int n = w * 16 + m;
        #pragma unroll
        for (int mt = 0; mt < 4; ++mt)
            #pragma unroll
            for (int r = 0; r < 4; ++r) {
                int R = mt * 16 + quad * 4 + r;
                float vv = fmaxf(acc2[mt][r] + b1v, 0.f);
                eA[(R >> 2) * 520 + (R & 3) * 128 + n] = f2h(vv);
            }
    }
    // ---- prefetch enc2 B before barrier (harmless if sunk) ----
    const int isB = w >> 2, nt2 = w & 3;
    const int nch2 = isB ? 12 : 8;
    const u16* Bp2 = wsu + (isB ? P_B2B : P_B2A);
    f16x8 pB2[12];
    #pragma unroll
    for (int ch = 0; ch < 8; ++ch) pB2[ch] = ffrag(Bp2, nt2, ch, nch2, lane);
    if (isB) {
        #pragma unroll
        for (int ch = 8; ch < 12; ++ch) pB2[ch] = ffrag(Bp2, nt2, ch, 12, lane);
    }
    __syncthreads();                                             // [3]
    // ---- enc2: b2 hoisted to phase top; waves 0-3 = A (K=256), 4-7 = B (K=384) ----
    {
        const float b2v = b2[nt2 * 16 + m];
        const int awoff = isB ? 128 : 0;
        f32x4 a2a = (f32x4){0.f, 0.f, 0.f, 0.f};
        f32x4 a2b = (f32x4){0.f, 0.f, 0.f, 0.f};
        #pragma unroll
        for (int ch = 0; ch < 8; ++ch) {
            int phys = m * 520 + awoff + ch * 32 + quad * 8;
            f16x8 ah = *(const f16x8*)(eA + phys);
            if (ch & 1) a2b = MFMA16(ah, pB2[ch], a2b);
            else        a2a = MFMA16(ah, pB2[ch], a2a);
        }
        if (isB) {
            #pragma unroll
            for (int ch = 8; ch < 12; ++ch) {
                int phys = m * 520 + awoff + ch * 32 + quad * 8;
                f16x8 ah = *(const f16x8*)(eA + phys);
                if (ch & 1) a2b = MFMA16(ah, pB2[ch], a2b);
                else        a2a = MFMA16(ah, pB2[ch], a2a);
            }
        }
        const int oc = nt2 * 16 + m;
        const int col = isB * 64 + oc;
        #pragma unroll
        for (int r = 0; r < 4; ++r) {
            int row = quad * 4 + r;
            float vv = fmaxf(a2a[r] + a2b[r] + b2v, 0.f);
            s2[row * 136 + col] = f2h(vv);
        }
    }
    // ---- prefetch enc3 B before barrier (waves 0-3; harmless if sunk) ----
    f16x8 pB3[4];
    if (w < 4) {
        #pragma unroll
        for (int ch = 0; ch < 4; ++ch) pB3[ch] = ffrag(wsu + P_B3, w, ch, 4, lane);
    }
    __syncthreads();                                             // [4]
    // ---- enc3: b3 hoisted to phase top; waves 0-3, K=128 (4 ch), N=64 ----
    if (w < 4) {
        const float b3v = b3[w * 16 + m];
        f32x4 a3a = (f32x4){0.f, 0.f, 0.f, 0.f};
        f32x4 a3b = (f32x4){0.f, 0.f, 0.f, 0.f};
        #pragma unroll
        for (int ch = 0; ch < 4; ++ch) {
            int phys = m * 136 + ch * 32 + quad * 8;
            f16x8 ah = *(const f16x8*)(s2 + phys);
            if (ch & 1) a3b = MFMA16(ah, pB3[ch], a3b);
            else        a3a = MFMA16(ah, pB3[ch], a3a);
        }
        const int n = w * 16 + m;
        #pragma unroll
        for (int r = 0; r < 4; ++r) {
            int row = quad * 4 + r;
            float vv = fmaxf(a3a[r] + a3b[r] + b3v, 0.f);
            s3[row * 72 + n] = f2h(vv);
        }
    }
    // ---- prefetch enc4 B before barrier (harmless if sunk) ----
    f16x8 pB4[2];
    #pragma unroll
    for (int ch = 0; ch < 2; ++ch) pB4[ch] = ffrag(wsu + P_B4, w, ch, 2, lane);
    __syncthreads();                                             // [5]
    // ---- enc4: b4 hoisted to phase top; all 8 waves, K=64 (2 ch), N=128 ----
    {
        const float b4v = b4[w * 16 + m];
        f32x4 a4a = (f32x4){0.f, 0.f, 0.f, 0.f};
        f32x4 a4b = (f32x4){0.f, 0.f, 0.f, 0.f};
        {
            int phys = m * 72 + 0 * 32 + quad * 8;
            a4a = MFMA16(*(const f16x8*)(s3 + phys), pB4[0], a4a);
            phys = m * 72 + 1 * 32 + quad * 8;
            a4b = MFMA16(*(const f16x8*)(s3 + phys), pB4[1], a4b);
        }
        const int n = w * 16 + m;
        #pragma unroll
        for (int r = 0; r < 4; ++r) {
            int row = quad * 4 + r;
            float vv = fmaxf(a4a[r] + a4b[r] + b4v, 0.f);
            xh[row * 264 + n] = f2h(vv);
        }
    }
    // ---- prefetch LSTM B for ch 0-1 before barrier (harmless if sunk) ----
    const u16* BLp = wsu + P_BL;
    f16x8 pBL[8];
    #pragma unroll
    for (int ch = 0; ch < 2; ++ch)
        #pragma unroll
        for (int g = 0; g < 4; ++g)
            pBL[g * 2 + ch] = ffrag(BLp, g * 8 + w, ch, 8, lane);
    __syncthreads();                                             // [6]
    // ---- LSTM: biases/cw/cin hoisted to phase top (hide under 64 MFMAs) ----
    {
        const int j = w * 16 + m;
        const float biV = bxi[j] + bhi[j];
        const float bfV = bxf[j] + bhf[j];
        const float bgV = bxg[j] + bhg[j];
        const float boV = bxo[j] + bho[j];
        const float cwV = cw[j];
        float ci4[4];
        #pragma unroll
        for (int r = 0; r < 4; ++r)
            ci4[r] = cin[(size_t)(b0 + quad * 4 + r) * 128 + j];
        f32x4 agA[4], agB[4];
        #pragma unroll
        for (int g = 0; g < 4; ++g) {
            agA[g] = (f32x4){0.f, 0.f, 0.f, 0.f};
            agB[g] = (f32x4){0.f, 0.f, 0.f, 0.f};
        }
        #pragma unroll
        for (int ch = 0; ch < 8; ++ch) {
            int phys = m * 264 + ch * 32 + quad * 8;
            f16x8 ah = *(const f16x8*)(xh + phys);
            #pragma unroll
            for (int g = 0; g < 4; ++g) {
                f16x8 bh = (ch < 2) ? pBL[g * 2 + ch] : ffrag(BLp, g * 8 + w, ch, 8, lane);
                if (ch & 1) agB[g] = MFMA16(ah, bh, agB[g]);
                else        agA[g] = MFMA16(ah, bh, agA[g]);
            }
        }
        float partial[4];
        #pragma unroll
        for (int r = 0; r < 4; ++r) {
            const int b = b0 + quad * 4 + r;
            const float ig = sigm(agA[0][r] + agB[0][r] + biV);
            const float fg = sigm(agA[1][r] + agB[1][r] + bfV);
            const float gg = tanh_fast(agA[2][r] + agB[2][r] + bgV);
            const float og = sigm(agA[3][r] + agB[3][r] + boV);
            const float co = fg * ci4[r] + ig * gg;
            const float ho = og * tanh_fast(co);
            out[(size_t)BATCH + (size_t)b * 128 + j] = ho;
            out[(size_t)BATCH + (size_t)BATCH * 128 + (size_t)b * 128 + j] = co;
            partial[r] = fmaxf(ho, 0.f) * cwV;
        }
        #pragma unroll
        for (int off = 1; off < 16; off <<= 1)
            #pragma unroll
            for (int r = 0; r < 4; ++r) partial[r] += __shfl_xor(partial[r], off);
        if (m == 0) {
            #pragma unroll
            for (int r = 0; r < 4; ++r) pr[w * 16 + quad * 4 + r] = partial[r];
        }
    }
    __syncthreads();                                             // [7]
    if (tid < 16) {
        float s = cb[0];
        #pragma unroll
        for (int g = 0; g < 8; ++g) s += pr[g * 16 + tid];
        out[b0 + tid] = sigm(s);
    }
}

extern "C" void kernel_launch(void* const* d_in, const int* in_sizes, int n_in,
                              void* d_out, int out_size, void* d_ws, size_t ws_size,
                              hipStream_t stream) {
    const float* audio = (const float*)d_in[0];
    const float* hin   = (const float*)d_in[1];
    const float* cin   = (const float*)d_in[2];
    const float* fb    = (const float*)d_in[3];
    const float* w1    = (const float*)d_in[4];
    const float* b1    = (const float*)d_in[5];
    const float* w2    = (const float*)d_in[6];
    const float* b2    = (const float*)d_in[7];
    const float* w3    = (const float*)d_in[8];
    const float* b3    = (const float*)d_in[9];
    const float* w4    = (const float*)d_in[10];
    const float* b4    = (const float*)d_in[11];
    const float* wi    = (const float*)d_in[12];
    const float* wf    = (const float*)d_in[13];
    const float* wg    = (const float*)d_in[14];
    const float* wo    = (const float*)d_in[15];
    const float* ui    = (const float*)d_in[16];
    const float* uf    = (const float*)d_in[17];
    const float* ug    = (const float*)d_in[18];
    const float* uo    = (const float*)d_in[19];
    const float* bxi   = (const float*)d_in[20];
    const float* bxf   = (const float*)d_in[21];
    const float* bxg   = (const float*)d_in[22];
    const float* bxo   = (const float*)d_in[23];
    const float* bhi   = (const float*)d_in[24];
    const float* bhf   = (const float*)d_in[25];
    const float* bhg   = (const float*)d_in[26];
    const float* bho   = (const float*)d_in[27];
    const float* cw    = (const float*)d_in[28];
    const float* cb    = (const float*)d_in[29];
    float* out = (float*)d_out;

    u16* wsu = (u16*)d_ws;

    k_prep<<<640, 256, 0, stream>>>(fb, w1, w2, w3, w4, wi, wf, wg, wo, ui, uf, ug, uo, wsu);
    k_all<<<BATCH / 16, 512, 0, stream>>>(audio, wsu, hin, cin, b1, b2, b3, b4,
                                          bxi, bxf, bxg, bxo, bhi, bhf, bhg, bho,
                                          cw, cb, out);
}

// Round 12
// 153.455 us; speedup vs baseline: 1.0796x; 1.0796x over previous
//
#include <hip/hip_runtime.h>
#include <math.h>

#define BATCH 8192
typedef unsigned short u16;
typedef unsigned int u32;
typedef _Float16 f16;
typedef __attribute__((ext_vector_type(8))) _Float16 f16x8;
typedef __attribute__((ext_vector_type(4))) float f32x4;
typedef __attribute__((ext_vector_type(4))) unsigned short u16x4;

__device__ __forceinline__ float sigm(float v) { return 1.0f / (1.0f + __expf(-v)); }
__device__ __forceinline__ u16 f2h(float f) {
    union { f16 h; u16 u; } v; v.h = (f16)f;   // v_cvt_f16_f32, RNE
    return v.u;
}
// fragment-linear B: element [(nt*nch + ch)*64 + lane]*8 + e  ==  B[nt*16+(lane&15)][ch*32+(lane>>4)*8+e]
__device__ __forceinline__ f16x8 ffrag(const u16* Bf, int nt, int ch, int nch, int lane) {
    return *(const f16x8*)(Bf + (((size_t)nt * nch + ch) * 64 + lane) * 8);
}
#define MFMA16(a, b, c) __builtin_amdgcn_mfma_f32_16x16x32_f16(a, b, c, 0, 0, 0)

// ---------------- workspace layout (u16 elements, fp16, SINGLE plane) ----------------
#define S_FBT 69632   // [17 nt][8 ch] frag-linear, n<272, k<256
#define S_B1  61440   // 3 taps x [8 nt][5 ch], n<128, k<160
#define S_B2A 16384   // [4 nt][8 ch]
#define S_B2B 24576   // [4 nt][12 ch]
#define S_B3  8192    // [4 nt][4 ch]
#define S_B4  8192    // [8 nt][2 ch]
#define S_BL  131072  // [32 nt][8 ch]  n = gate*128+j, k: 0..127 W / 128..255 U
#define P_FBT 0
#define P_B1  69632
#define P_B2A 131072
#define P_B2B 147456
#define P_B3  172032
#define P_B4  180224
#define P_BL  188416
#define N_PREP 319488

// ---------------- k_prep: build fragment-linear fp16 B planes ----------------
__global__ __launch_bounds__(256) void k_prep(const float* __restrict__ fb,
                                              const float* __restrict__ w1, const float* __restrict__ w2,
                                              const float* __restrict__ w3, const float* __restrict__ w4,
                                              const float* __restrict__ wi, const float* __restrict__ wf,
                                              const float* __restrict__ wg, const float* __restrict__ wo,
                                              const float* __restrict__ ui, const float* __restrict__ uf,
                                              const float* __restrict__ ug, const float* __restrict__ uo,
                                              u16* __restrict__ wsu) {
    const float* Ws[8] = {wi, wf, wg, wo, ui, uf, ug, uo};
    for (int i = blockIdx.x * 256 + threadIdx.x; i < N_PREP; i += gridDim.x * 256) {
        int r = i;
        float v; int P, idx;
        if (r < S_FBT) {                                    // FBT nch=8
            int f = r >> 9, lane = (r & 511) >> 3, e = r & 7;
            int n = (f >> 3) * 16 + (lane & 15), k = (f & 7) * 32 + (lane >> 4) * 8 + e;
            int c = n >> 1, part = n & 1;
            v = (n < 258) ? fb[(size_t)(c + part * 129) * 256 + k] : 0.f;
            P = P_FBT; idx = r;
        } else if ((r -= S_FBT) < S_B1) {                   // B1: 3 taps, nch=5
            int kk = r / 20480, r2 = r - kk * 20480;
            int f = r2 >> 9, lane = (r2 & 511) >> 3, e = r2 & 7;
            int n = (f / 5) * 16 + (lane & 15), k = (f % 5) * 32 + (lane >> 4) * 8 + e;
            v = (k < 129) ? w1[(size_t)n * 387 + k * 3 + kk] : 0.f;
            P = P_B1; idx = r;
        } else if ((r -= S_B1) < S_B2A) {                   // B2A nch=8
            int f = r >> 9, lane = (r & 511) >> 3, e = r & 7;
            int n = (f >> 3) * 16 + (lane & 15), k = (f & 7) * 32 + (lane >> 4) * 8 + e;
            v = w2[(size_t)n * 384 + (k & 127) * 3 + (k >> 7) + 1];
            P = P_B2A; idx = r;
        } else if ((r -= S_B2A) < S_B2B) {                  // B2B nch=12
            int f = r >> 9, lane = (r & 511) >> 3, e = r & 7;
            int n = (f / 12) * 16 + (lane & 15), k = (f % 12) * 32 + (lane >> 4) * 8 + e;
            v = w2[(size_t)n * 384 + (k & 127) * 3 + (k >> 7)];
            P = P_B2B; idx = r;
        } else if ((r -= S_B2B) < S_B3) {                   // B3 nch=4
            int f = r >> 9, lane = (r & 511) >> 3, e = r & 7;
            int n = (f >> 2) * 16 + (lane & 15), k = (f & 3) * 32 + (lane >> 4) * 8 + e;
            v = w3[(size_t)n * 192 + (k & 63) * 3 + (k >> 6) + 1];
            P = P_B3; idx = r;
        } else if ((r -= S_B3) < S_B4) {                    // B4 nch=2
            int f = r >> 9, lane = (r & 511) >> 3, e = r & 7;
            int n = (f >> 1) * 16 + (lane & 15), k = (f & 1) * 32 + (lane >> 4) * 8 + e;
            v = w4[(size_t)n * 192 + k * 3 + 1];
            P = P_B4; idx = r;
        } else {                                            // BL nch=8
            r -= S_B4;
            int f = r >> 9, lane = (r & 511) >> 3, e = r & 7;
            int n = (f >> 3) * 16 + (lane & 15), k = (f & 7) * 32 + (lane >> 4) * 8 + e;
            int g = n >> 7, j = n & 127;
            v = Ws[g + ((k >= 128) ? 4 : 0)][(size_t)j * 128 + (k & 127)];
            P = P_BL; idx = r;
        }
        wsu[P + idx] = f2h(v);
    }
}

// ---------------- k_all ----------------
// r10 = measured best (dur 155.33, k_all < 42.4us fill-cutoff, absmax 0.007324219).
// 7 barriers, fp16 single-MFMA datapath, K-split dual accumulators, same-phase
// scalar-load hoists. REVERTED from r11: GEMM1 tile16-split caused VALUBusy 26->49%
// and +10us (codegen/pipelining damage in the largest phase); transcendental swap
// was innocent-by-arithmetic but rides along in the revert (r11 lesson: one change
// per round in codegen-sensitive regions).
__global__ __launch_bounds__(512, 4) void k_all(const float* __restrict__ audio,
                                             const u16* __restrict__ wsu,
                                             const float* __restrict__ hin, const float* __restrict__ cin,
                                             const float* __restrict__ b1, const float* __restrict__ b2,
                                             const float* __restrict__ b3, const float* __restrict__ b4,
                                             const float* __restrict__ bxi, const float* __restrict__ bxf,
                                             const float* __restrict__ bxg, const float* __restrict__ bxo,
                                             const float* __restrict__ bhi, const float* __restrict__ bhf,
                                             const float* __restrict__ bhg, const float* __restrict__ bho,
                                             const float* __restrict__ cw, const float* __restrict__ cb,
                                             float* __restrict__ out) {
    __shared__ __align__(16) u16 uni[31872];
    u16* aA = uni;
    u16* eA = uni;
    u16* mA = uni + 11520;
    u16* s2 = uni + 11520;
    u16* s3 = uni + 13696;
    float* pr = (float*)(uni + 14848);
    u16* xh = uni + 27648;
    const int tid = threadIdx.x;
    const int b0 = blockIdx.x << 4;
    const int lane = tid & 63, w = tid >> 6;
    const int m = lane & 15, quad = lane >> 4;
    // ---- phase A: stage audio + zero mag plane + stage h ----
    for (int i = tid; i < 16 * 160; i += 512) {
        int bb = i / 160, j4 = (i - bb * 160) * 4;
        const float* ap = audio + (size_t)(b0 + bb) * 576;
        float4 v;
        if (j4 < 576) v = *(const float4*)(ap + j4);
        else { v.x = ap[1150 - j4]; v.y = ap[1149 - j4]; v.z = ap[1148 - j4]; v.w = ap[1147 - j4]; }
        int phys = bb * 720 + j4 + (j4 >> 7) * 8;
        u16x4 hv = {f2h(v.x), f2h(v.y), f2h(v.z), f2h(v.w)};
        *(u16x4*)(aA + phys) = hv;
    }
    for (int i = tid; i < 8064; i += 512) ((u32*)mA)[i] = 0u;    // zero mag (pads)
    for (int i = tid; i < 16 * 32; i += 512) {
        int row = i >> 5, c4 = (i & 31) * 4;
        float4 v = *(const float4*)(hin + (size_t)(b0 + row) * 128 + c4);
        u16x4 hv = {f2h(v.x), f2h(v.y), f2h(v.z), f2h(v.w)};
        *(u16x4*)(xh + row * 264 + 128 + c4) = hv;
    }
    __syncthreads();                                             // [1]
    // ---- GEMM1 (STFT): wave w owns nt = 2w..2w+1 (w==7 also nt=16), mt=4 ----
    const u16* fbT = wsu + P_FBT;
    const int tcnt = (w == 7) ? 3 : 2;
    f32x4 acc[4][3];
    #pragma unroll
    for (int mt = 0; mt < 4; ++mt)
        #pragma unroll
        for (int t = 0; t < 3; ++t) acc[mt][t] = (f32x4){0.f, 0.f, 0.f, 0.f};
    for (int ch = 0; ch < 8; ++ch) {
        f16x8 ah[4];
        #pragma unroll
        for (int mt = 0; mt < 4; ++mt) {
            int Rm = mt * 16 + m;
            int phys = (Rm >> 2) * 720 + (Rm & 3) * 136 + ch * 32 + quad * 8 + ((ch >= 4) ? 8 : 0);
            ah[mt] = *(const f16x8*)(aA + phys);
        }
        #pragma unroll
        for (int tt = 0; tt < 3; ++tt) {
            if (tt < tcnt) {
                int t = w * 2 + tt;
                f16x8 bh = ffrag(fbT, t, ch, 8, lane);
                #pragma unroll
                for (int mt = 0; mt < 4; ++mt)
                    acc[mt][tt] = MFMA16(ah[mt], bh, acc[mt][tt]);
            }
        }
    }
    // ---- magnitude epilogue -> mag LDS (no barrier: disjoint per-wave cells) ----
    #pragma unroll
    for (int tt = 0; tt < 3; ++tt) {
        if (tt < tcnt) {
            int n = (w * 2 + tt) * 16 + m;
            #pragma unroll
            for (int mt = 0; mt < 4; ++mt)
                #pragma unroll
                for (int r = 0; r < 4; ++r) {
                    float vv = acc[mt][tt][r];
                    float s = vv * vv;
                    s += __shfl_xor(s, 1);
                    if (!(n & 1)) {
                        int R = mt * 16 + quad * 4 + r;
                        int bb = R >> 2, t = R & 3, c = n >> 1;
                        mA[(bb * 6 + t + 1) * 168 + c] = f2h(sqrtf(s));
                    }
                }
        }
    }
    // ---- prefetch enc1 B (15 frags) before barrier (harmless if sunk) ----
    const u16* B1p = wsu + P_B1;
    f16x8 pB1[15];
    #pragma unroll
    for (int kk = 0; kk < 3; ++kk)
        #pragma unroll
        for (int ch = 0; ch < 5; ++ch)
            pB1[kk * 5 + ch] = ffrag(B1p + kk * 20480, w, ch, 5, lane);
    __syncthreads();                                             // [2]
    // ---- GEMM2 (enc1): b1 hoisted to phase top; wave w owns nt = w, mt=4 ----
    const float b1v = b1[w * 16 + m];
    f32x4 acc2[4];
    #pragma unroll
    for (int mt = 0; mt < 4; ++mt) acc2[mt] = (f32x4){0.f, 0.f, 0.f, 0.f};
    #pragma unroll
    for (int kk = 0; kk < 3; ++kk) {
        #pragma unroll
        for (int ch = 0; ch < 5; ++ch) {
            f16x8 bh = pB1[kk * 5 + ch];
            #pragma unroll
            for (int mt = 0; mt < 4; ++mt) {
                int Rm = mt * 16 + m;
                int phys = ((Rm >> 2) * 6 + (Rm & 3) + kk) * 168 + ch * 32 + quad * 8;
                f16x8 ah = *(const f16x8*)(mA + phys);
                acc2[mt] = MFMA16(ah, bh, acc2[mt]);
            }
        }
    }
    // ---- e1 -> eA (aliases dead audio; no barrier) ----
    {
        int n = w * 16 + m;
        #pragma unroll
        for (int mt = 0; mt < 4; ++mt)
            #pragma unroll
            for (int r = 0; r < 4; ++r) {
                int R = mt * 16 + quad * 4 + r;
                float vv = fmaxf(acc2[mt][r] + b1v, 0.f);
                eA[(R >> 2) * 520 + (R & 3) * 128 + n] = f2h(vv);
            }
    }
    // ---- prefetch enc2 B before barrier (harmless if sunk) ----
    const int isB = w >> 2, nt2 = w & 3;
    const int nch2 = isB ? 12 : 8;
    const u16* Bp2 = wsu + (isB ? P_B2B : P_B2A);
    f16x8 pB2[12];
    #pragma unroll
    for (int ch = 0; ch < 8; ++ch) pB2[ch] = ffrag(Bp2, nt2, ch, nch2, lane);
    if (isB) {
        #pragma unroll
        for (int ch = 8; ch < 12; ++ch) pB2[ch] = ffrag(Bp2, nt2, ch, 12, lane);
    }
    __syncthreads();                                             // [3]
    // ---- enc2: b2 hoisted to phase top; waves 0-3 = A (K=256), 4-7 = B (K=384) ----
    {
        const float b2v = b2[nt2 * 16 + m];
        const int awoff = isB ? 128 : 0;
        f32x4 a2a = (f32x4){0.f, 0.f, 0.f, 0.f};
        f32x4 a2b = (f32x4){0.f, 0.f, 0.f, 0.f};
        #pragma unroll
        for (int ch = 0; ch < 8; ++ch) {
            int phys = m * 520 + awoff + ch * 32 + quad * 8;
            f16x8 ah = *(const f16x8*)(eA + phys);
            if (ch & 1) a2b = MFMA16(ah, pB2[ch], a2b);
            else        a2a = MFMA16(ah, pB2[ch], a2a);
        }
        if (isB) {
            #pragma unroll
            for (int ch = 8; ch < 12; ++ch) {
                int phys = m * 520 + awoff + ch * 32 + quad * 8;
                f16x8 ah = *(const f16x8*)(eA + phys);
                if (ch & 1) a2b = MFMA16(ah, pB2[ch], a2b);
                else        a2a = MFMA16(ah, pB2[ch], a2a);
            }
        }
        const int oc = nt2 * 16 + m;
        const int col = isB * 64 + oc;
        #pragma unroll
        for (int r = 0; r < 4; ++r) {
            int row = quad * 4 + r;
            float vv = fmaxf(a2a[r] + a2b[r] + b2v, 0.f);
            s2[row * 136 + col] = f2h(vv);
        }
    }
    // ---- prefetch enc3 B before barrier (waves 0-3; harmless if sunk) ----
    f16x8 pB3[4];
    if (w < 4) {
        #pragma unroll
        for (int ch = 0; ch < 4; ++ch) pB3[ch] = ffrag(wsu + P_B3, w, ch, 4, lane);
    }
    __syncthreads();                                             // [4]
    // ---- enc3: b3 hoisted to phase top; waves 0-3, K=128 (4 ch), N=64 ----
    if (w < 4) {
        const float b3v = b3[w * 16 + m];
        f32x4 a3a = (f32x4){0.f, 0.f, 0.f, 0.f};
        f32x4 a3b = (f32x4){0.f, 0.f, 0.f, 0.f};
        #pragma unroll
        for (int ch = 0; ch < 4; ++ch) {
            int phys = m * 136 + ch * 32 + quad * 8;
            f16x8 ah = *(const f16x8*)(s2 + phys);
            if (ch & 1) a3b = MFMA16(ah, pB3[ch], a3b);
            else        a3a = MFMA16(ah, pB3[ch], a3a);
        }
        const int n = w * 16 + m;
        #pragma unroll
        for (int r = 0; r < 4; ++r) {
            int row = quad * 4 + r;
            float vv = fmaxf(a3a[r] + a3b[r] + b3v, 0.f);
            s3[row * 72 + n] = f2h(vv);
        }
    }
    // ---- prefetch enc4 B before barrier (harmless if sunk) ----
    f16x8 pB4[2];
    #pragma unroll
    for (int ch = 0; ch < 2; ++ch) pB4[ch] = ffrag(wsu + P_B4, w, ch, 2, lane);
    __syncthreads();                                             // [5]
    // ---- enc4: b4 hoisted to phase top; all 8 waves, K=64 (2 ch), N=128 ----
    {
        const float b4v = b4[w * 16 + m];
        f32x4 a4a = (f32x4){0.f, 0.f, 0.f, 0.f};
        f32x4 a4b = (f32x4){0.f, 0.f, 0.f, 0.f};
        {
            int phys = m * 72 + 0 * 32 + quad * 8;
            a4a = MFMA16(*(const f16x8*)(s3 + phys), pB4[0], a4a);
            phys = m * 72 + 1 * 32 + quad * 8;
            a4b = MFMA16(*(const f16x8*)(s3 + phys), pB4[1], a4b);
        }
        const int n = w * 16 + m;
        #pragma unroll
        for (int r = 0; r < 4; ++r) {
            int row = quad * 4 + r;
            float vv = fmaxf(a4a[r] + a4b[r] + b4v, 0.f);
            xh[row * 264 + n] = f2h(vv);
        }
    }
    // ---- prefetch LSTM B for ch 0-1 before barrier (harmless if sunk) ----
    const u16* BLp = wsu + P_BL;
    f16x8 pBL[8];
    #pragma unroll
    for (int ch = 0; ch < 2; ++ch)
        #pragma unroll
        for (int g = 0; g < 4; ++g)
            pBL[g * 2 + ch] = ffrag(BLp, g * 8 + w, ch, 8, lane);
    __syncthreads();                                             // [6]
    // ---- LSTM: biases/cw/cin hoisted to phase top (cold-HBM cin hides under 64 MFMAs) ----
    {
        const int j = w * 16 + m;
        const float biV = bxi[j] + bhi[j];
        const float bfV = bxf[j] + bhf[j];
        const float bgV = bxg[j] + bhg[j];
        const float boV = bxo[j] + bho[j];
        const float cwV = cw[j];
        float ci4[4];
        #pragma unroll
        for (int r = 0; r < 4; ++r)
            ci4[r] = cin[(size_t)(b0 + quad * 4 + r) * 128 + j];
        f32x4 agA[4], agB[4];
        #pragma unroll
        for (int g = 0; g < 4; ++g) {
            agA[g] = (f32x4){0.f, 0.f, 0.f, 0.f};
            agB[g] = (f32x4){0.f, 0.f, 0.f, 0.f};
        }
        #pragma unroll
        for (int ch = 0; ch < 8; ++ch) {
            int phys = m * 264 + ch * 32 + quad * 8;
            f16x8 ah = *(const f16x8*)(xh + phys);
            #pragma unroll
            for (int g = 0; g < 4; ++g) {
                f16x8 bh = (ch < 2) ? pBL[g * 2 + ch] : ffrag(BLp, g * 8 + w, ch, 8, lane);
                if (ch & 1) agB[g] = MFMA16(ah, bh, agB[g]);
                else        agA[g] = MFMA16(ah, bh, agA[g]);
            }
        }
        float partial[4];
        #pragma unroll
        for (int r = 0; r < 4; ++r) {
            const int b = b0 + quad * 4 + r;
            const float ig = sigm(agA[0][r] + agB[0][r] + biV);
            const float fg = sigm(agA[1][r] + agB[1][r] + bfV);
            const float gg = tanhf(agA[2][r] + agB[2][r] + bgV);
            const float og = sigm(agA[3][r] + agB[3][r] + boV);
            const float co = fg * ci4[r] + ig * gg;
            const float ho = og * tanhf(co);
            out[(size_t)BATCH + (size_t)b * 128 + j] = ho;
            out[(size_t)BATCH + (size_t)BATCH * 128 + (size_t)b * 128 + j] = co;
            partial[r] = fmaxf(ho, 0.f) * cwV;
        }
        #pragma unroll
        for (int off = 1; off < 16; off <<= 1)
            #pragma unroll
            for (int r = 0; r < 4; ++r) partial[r] += __shfl_xor(partial[r], off);
        if (m == 0) {
            #pragma unroll
            for (int r = 0; r < 4; ++r) pr[w * 16 + quad * 4 + r] = partial[r];
        }
    }
    __syncthreads();                                             // [7]
    if (tid < 16) {
        float s = cb[0];
        #pragma unroll
        for (int g = 0; g < 8; ++g) s += pr[g * 16 + tid];
        out[b0 + tid] = sigm(s);
    }
}

extern "C" void kernel_launch(void* const* d_in, const int* in_sizes, int n_in,
                              void* d_out, int out_size, void* d_ws, size_t ws_size,
                              hipStream_t stream) {
    const float* audio = (const float*)d_in[0];
    const float* hin   = (const float*)d_in[1];
    const float* cin   = (const float*)d_in[2];
    const float* fb    = (const float*)d_in[3];
    const float* w1    = (const float*)d_in[4];
    const float* b1    = (const float*)d_in[5];
    const float* w2    = (const float*)d_in[6];
    const float* b2    = (const float*)d_in[7];
    const float* w3    = (const float*)d_in[8];
    const float* b3    = (const float*)d_in[9];
    const float* w4    = (const float*)d_in[10];
    const float* b4    = (const float*)d_in[11];
    const float* wi    = (const float*)d_in[12];
    const float* wf    = (const float*)d_in[13];
    const float* wg    = (const float*)d_in[14];
    const float* wo    = (const float*)d_in[15];
    const float* ui    = (const float*)d_in[16];
    const float* uf    = (const float*)d_in[17];
    const float* ug    = (const float*)d_in[18];
    const float* uo    = (const float*)d_in[19];
    const float* bxi   = (const float*)d_in[20];
    const float* bxf   = (const float*)d_in[21];
    const float* bxg   = (const float*)d_in[22];
    const float* bxo   = (const float*)d_in[23];
    const float* bhi   = (const float*)d_in[24];
    const float* bhf   = (const float*)d_in[25];
    const float* bhg   = (const float*)d_in[26];
    const float* bho   = (const float*)d_in[27];
    const float* cw    = (const float*)d_in[28];
    const float* cb    = (const float*)d_in[29];
    float* out = (float*)d_out;

    u16* wsu = (u16*)d_ws;

    k_prep<<<640, 256, 0, stream>>>(fb, w1, w2, w3, w4, wi, wf, wg, wo, ui, uf, ug, uo, wsu);
    k_all<<<BATCH / 16, 512, 0, stream>>>(audio, wsu, hin, cin, b1, b2, b3, b4,
                                          bxi, bxf, bxg, bxo, bhi, bhf, bhg, bho,
                                          cw, cb, out);
}